// Round 18
// baseline (1106.541 us; speedup 1.0000x reference)
//
#include <hip/hip_runtime.h>
#include <hip/hip_bf16.h>
#include <math.h>

#define NSL 4
#define DM 1024
#define NH 16
#define DKH 64
#define DFF 4096
#define BB 2
#define LL 512
#define VTOK 32000

typedef short s16x8 __attribute__((ext_vector_type(8)));
typedef float f32x4 __attribute__((ext_vector_type(4)));

__device__ __forceinline__ void gload16(const void* g, void* l) {
  __builtin_amdgcn_global_load_lds((__attribute__((address_space(1))) void*)g,
                                   (__attribute__((address_space(3))) void*)l, 16, 0, 0);
}

// ---------------------------------------------------------------- PE table (pos,dim) -> final additive value
__global__ __launch_bounds__(256) void pe_table_kernel(float* __restrict__ pet) {
  const int idx = blockIdx.x * 256 + threadIdx.x;   // LL*DM
  const int dim = idx & (DM - 1);
  const int pos = idx >> 10;
  const float denum = powf(10000.0f, (2.0f * (float)dim) / (float)DM);
  const float pe = (float)pos / denum;
  pet[idx] = (dim & 1) ? cosf(pe) : (1.0f + sinf(pe));
}

// ---------------------------------------------------------------- embedding (both streams, z-batched, PE table)
__global__ __launch_bounds__(256) void embed2_kernel(
    const int* __restrict__ toks, const int* __restrict__ tokt,
    const float* __restrict__ ws, const float* __restrict__ wt,
    const float* __restrict__ pet,
    float* __restrict__ eo, __hip_bfloat16* __restrict__ eobf,
    float* __restrict__ dco, __hip_bfloat16* __restrict__ dcobf) {
  const int which = blockIdx.y;
  const int* tok = which ? tokt : toks;
  const float* w = which ? wt : ws;
  float* o = which ? dco : eo;
  __hip_bfloat16* obf = which ? dcobf : eobf;
  const int idx = blockIdx.x * 256 + threadIdx.x;   // BB*LL*DM
  const int dim = idx & (DM - 1);
  const int pos = (idx >> 10) & (LL - 1);
  const int b   = idx >> 19;
  const int token = tok[b * LL + pos];
  const float r = w[(size_t)token * DM + dim] + pet[pos * DM + dim];
  o[idx] = r;
  obf[idx] = __float2bfloat16(r);
}

// ---------------------------------------------------------------- multi-job weight transpose
struct TJobs {
  const float* src[8];
  __hip_bfloat16* dst[8];
  int K[8];
  int N[8];
  int tiles[8];
  int njobs;
};

__global__ __launch_bounds__(256) void transpose_multi(TJobs jobs) {
  __shared__ float tb[64][65];
  int t = blockIdx.x;
  int ji = 0;
  while (t >= jobs.tiles[ji]) { t -= jobs.tiles[ji]; ++ji; }
  const int K = jobs.K[ji], N = jobs.N[ji];
  const int tpx = N >> 6;
  const int tpm = tpx * (K >> 6);
  const int mat = t / tpm;
  const int t2 = t - mat * tpm;
  const float* src = jobs.src[ji] + (long)mat * K * N;
  __hip_bfloat16* dst = jobs.dst[ji] + (long)mat * K * N;
  const int n0 = (t2 % tpx) * 64, k0 = (t2 / tpx) * 64;
  const int lc = (threadIdx.x & 15) * 4;
  const int lr = threadIdx.x >> 4;
  #pragma unroll
  for (int u = 0; u < 4; ++u) {
    const int r = lr + u * 16;
    const float4 v = *(const float4*)(src + (long)(k0 + r) * N + n0 + lc);
    tb[r][lc + 0] = v.x; tb[r][lc + 1] = v.y; tb[r][lc + 2] = v.z; tb[r][lc + 3] = v.w;
  }
  __syncthreads();
  #pragma unroll
  for (int u = 0; u < 4; ++u) {
    const int r = lr + u * 16;
    ushort4 o;
    __hip_bfloat16 h0 = __float2bfloat16(tb[lc + 0][r]);
    __hip_bfloat16 h1 = __float2bfloat16(tb[lc + 1][r]);
    __hip_bfloat16 h2 = __float2bfloat16(tb[lc + 2][r]);
    __hip_bfloat16 h3 = __float2bfloat16(tb[lc + 3][r]);
    o.x = *(unsigned short*)&h0; o.y = *(unsigned short*)&h1;
    o.z = *(unsigned short*)&h2; o.w = *(unsigned short*)&h3;
    *(ushort4*)(dst + (long)(n0 + r) * K + k0 + lc) = o;
  }
}

// ---------------------------------------------------------------- MFMA GEMM (counted-vmcnt dbuf pipeline)
// C[M,N] = A[M,K] @ BT[N,K]^T + bias (+res) ; A,BT bf16 k-contiguous.
// VTM=0 none; 1: cols>=vt_off -> vt[b][d][j]; 2: mega-kv V halves -> vt+(bn>>11)*vt_stride.
// BMAP=1: bias indexed as dec_qkv2_b kv-stack. NTC=1: LDS-staged coalesced nontemporal fp32 C.
template<int BM, int BN, int BK, int RELU, int OBF, int SWZ, int VTM, int BMAP, int NTC>
__global__ __launch_bounds__(256, 2) void gemm_mfma(
    const __hip_bfloat16* __restrict__ A, const __hip_bfloat16* __restrict__ BT,
    const float* __restrict__ bias, void* __restrict__ Cout,
    int K, int lda, int ldb, int ldc,
    const float* __restrict__ res, __hip_bfloat16* __restrict__ obf2,
    __hip_bfloat16* __restrict__ vt, int vt_off, long vt_stride) {
  constexpr int WR = BM / 2, WC = BN / 2;
  constexpr int MF = WR / 16, NF = WC / 16;
  constexpr int CHK = BK / 8;            // 16B chunks per row
  constexpr int RPC = 64 / CHK;          // rows per wave-call
  constexpr int ACALLS = BM / RPC / 4, BCALLS = BN / RPC / 4;
  constexpr int NLOADS = ACALLS + BCALLS;
  constexpr int KSUB = BK / 32;          // MFMA k sub-steps per tile
  constexpr int ABUF = BM * BK, BBUF = BN * BK;
  constexpr int STAGE_BYTES = 2 * (ABUF + BBUF) * 2;
  constexpr int TT_BYTES = (VTM != 0) ? (BM * BN * 2) : 0;
  constexpr int CF_BYTES = NTC ? ((BM / 2) * BN * 4) : 0;   // 64-row fp32 staging
  constexpr int SMEM_A = STAGE_BYTES > TT_BYTES ? STAGE_BYTES : TT_BYTES;
  constexpr int SMEM_BYTES = SMEM_A > CF_BYTES ? SMEM_A : CF_BYTES;
  __shared__ __align__(16) char smem[SMEM_BYTES];
  __hip_bfloat16* As = (__hip_bfloat16*)smem;                          // [2][ABUF]
  __hip_bfloat16* Bs = (__hip_bfloat16*)(smem + (size_t)2 * ABUF * 2); // [2][BBUF]
  unsigned short* TT = (unsigned short*)smem;   // epilogue reuse

  int bx = blockIdx.x, by = blockIdx.y;
  if (SWZ) {
    const int gx = gridDim.x;
    const int nwg = gx * gridDim.y;     // caller guarantees %8==0
    const int id = by * gx + bx;
    const int qq = nwg >> 3;
    const int swz = (id & 7) * qq + (id >> 3);
    bx = swz % gx; by = swz / gx;
  }
  const int bm = by * BM, bn = bx * BN;
  const int tid = threadIdx.x, lane = tid & 63, wid = tid >> 6;
  const int wr = (wid >> 1) * WR, wc = (wid & 1) * WC;
  const int frow = lane & 15, fkc = lane >> 4;

  // XOR chunk swizzle (pre-swizzled SOURCE + same rule on read — rule #21)
  auto swz_chk = [](int c, int r) {
    if (BK == 32)      return c ^ ((r >> 1) & 3);
    else if (BK == 64) return c ^ (r & 7);
    else               return c ^ (r & 15);
  };

  const int s_row = lane / CHK;          // row within call
  const int s_chk = lane % CHK;

  auto stageAB = [&](int buf, int k0) {
    #pragma unroll
    for (int c = 0; c < ACALLS; ++c) {
      const int R0 = (wid * ACALLS + c) * RPC;
      const int row = R0 + s_row;
      gload16(A + (long)(bm + row) * lda + k0 + swz_chk(s_chk, row) * 8,
              As + buf * ABUF + R0 * BK);
    }
    #pragma unroll
    for (int c = 0; c < BCALLS; ++c) {
      const int R0 = (wid * BCALLS + c) * RPC;
      const int row = R0 + s_row;
      gload16(BT + (long)(bn + row) * ldb + k0 + swz_chk(s_chk, row) * 8,
              Bs + buf * BBUF + R0 * BK);
    }
  };

  f32x4 acc[MF][NF] = {};
  const int nt = K / BK;
  stageAB(0, 0);
  for (int t = 0; t < nt; ++t) {
    const int cur = t & 1;
    const bool more = (t + 1 < nt);
    if (more) {
      stageAB(cur ^ 1, (t + 1) * BK);                    // next tile stays in flight
      asm volatile("s_waitcnt vmcnt(%0)" :: "n"(NLOADS) : "memory");  // oldest = tile t landed
    } else {
      asm volatile("s_waitcnt vmcnt(0)" ::: "memory");
    }
    __builtin_amdgcn_s_barrier();                        // tile t globally visible
    asm volatile("" ::: "memory");
    #pragma unroll
    for (int s = 0; s < KSUB; ++s) {
      s16x8 af[MF], bfr[NF];
      #pragma unroll
      for (int mm = 0; mm < MF; ++mm) {
        const int r = wr + mm * 16 + frow;
        af[mm] = *(const s16x8*)&As[cur * ABUF + r * BK + swz_chk(s * 4 + fkc, r) * 8];
      }
      #pragma unroll
      for (int nn = 0; nn < NF; ++nn) {
        const int r = wc + nn * 16 + frow;
        bfr[nn] = *(const s16x8*)&Bs[cur * BBUF + r * BK + swz_chk(s * 4 + fkc, r) * 8];
      }
      #pragma unroll
      for (int mm = 0; mm < MF; ++mm)
        #pragma unroll
        for (int nn = 0; nn < NF; ++nn)
          acc[mm][nn] = __builtin_amdgcn_mfma_f32_16x16x32_bf16(af[mm], bfr[nn], acc[mm][nn], 0, 0, 0);
    }
    asm volatile("s_waitcnt lgkmcnt(0)" ::: "memory");   // my frag reads complete
    __builtin_amdgcn_s_barrier();                        // buf cur may be overwritten next iter
  }

  if (NTC) {
    // LDS-staged coalesced nontemporal C write (full 128B lines, no L3 pollution)
    float* CF = (float*)smem;                            // [BM/2][BN] fp32
    #pragma unroll
    for (int half = 0; half < 2; ++half) {
      __syncthreads();                                   // protect CF reuse
      if ((wid >> 1) == half) {
        #pragma unroll
        for (int mm = 0; mm < MF; ++mm)
          #pragma unroll
          for (int nn = 0; nn < NF; ++nn) {
            const int col = wc + nn * 16 + frow;
            const float bs = bias[bn + col];
            #pragma unroll
            for (int j = 0; j < 4; ++j)
              CF[(mm * 16 + fkc * 4 + j) * BN + col] = acc[mm][nn][j] + bs;
          }
      }
      __syncthreads();
      constexpr int NPASS = (BM / 2) * BN / 4 / 256;
      #pragma unroll
      for (int ps = 0; ps < NPASS; ++ps) {
        const int idx = tid * 4 + ps * 1024;
        const int row = idx / BN, col = idx % BN;
        const f32x4 v = *(const f32x4*)&CF[row * BN + col];
        __builtin_nontemporal_store(
            v, (f32x4*)((float*)Cout + (long)(bm + half * (BM / 2) + row) * ldc + bn + col));
      }
    }
    return;
  }

  bool vt_blk = false;
  if (VTM == 1) vt_blk = (bn >= vt_off);
  if (VTM == 2) vt_blk = (((bn >> 10) & 1) == 1);

  #pragma unroll
  for (int mm = 0; mm < MF; ++mm)
    #pragma unroll
    for (int nn = 0; nn < NF; ++nn) {
      const int row0 = bm + wr + mm * 16 + fkc * 4;
      const int col  = bn + wc + nn * 16 + frow;
      float bs;
      if (BMAP) bs = bias[(col >> 11) * 3 * DM + DM + (col & 2047)];
      else      bs = bias[col];
      float vv[4];
      #pragma unroll
      for (int j = 0; j < 4; ++j) {
        float v = acc[mm][nn][j] + bs;
        if (RELU) v = fmaxf(v, 0.0f);
        const long ci = (long)(row0 + j) * ldc + col;
        if (res) v += res[ci];
        if (OBF) ((__hip_bfloat16*)Cout)[ci] = __float2bfloat16(v);
        else     ((float*)Cout)[ci] = v;
        if (obf2) obf2[ci] = __float2bfloat16(v);
        vv[j] = v;
      }
      if (VTM != 0 && vt_blk) {
        const int dl  = wc + nn * 16 + frow;
        const int jl0 = (wr + mm * 16 + fkc * 4) ^ ((dl & 7) << 3);
        ushort4 pk;
        __hip_bfloat16 h0 = __float2bfloat16(vv[0]);
        __hip_bfloat16 h1 = __float2bfloat16(vv[1]);
        __hip_bfloat16 h2 = __float2bfloat16(vv[2]);
        __hip_bfloat16 h3 = __float2bfloat16(vv[3]);
        pk.x = *(unsigned short*)&h0; pk.y = *(unsigned short*)&h1;
        pk.z = *(unsigned short*)&h2; pk.w = *(unsigned short*)&h3;
        *(ushort4*)&TT[dl * BM + jl0] = pk;
      }
    }

  if (VTM != 0 && vt_blk) {
    __syncthreads();
    constexpr int TPR = BM / 8;
    constexpr int RPP = 256 / TPR;
    constexpr int NP  = BN / RPP;
    const int jj = (tid % TPR) * 8;
    const int b = bm >> 9;
    const int jbase = bm & (LL - 1);
    const __hip_bfloat16* vtp;
    int dg0;
    if (VTM == 2) {
      vtp = vt + (long)(bn >> 11) * vt_stride;
      dg0 = bn & 1023;
    } else {
      vtp = vt;
      dg0 = bn - vt_off;
    }
    #pragma unroll
    for (int u = 0; u < NP; ++u) {
      const int dl = (tid / TPR) + u * RPP;
      const s16x8 val = *(const s16x8*)&TT[dl * BM + (jj ^ ((dl & 7) << 3))];
      *(s16x8*)((__hip_bfloat16*)vtp + ((long)(b * DM + dg0 + dl)) * LL + jbase + jj) = val;
    }
  }
}

// ---------------------------------------------------------------- flash attention (KVBLK=128, counted-vmcnt dbuf, T5)
template<int CAUSAL>
__global__ __launch_bounds__(256) void flash_attn(
    const __hip_bfloat16* __restrict__ Q, int ldq,
    const __hip_bfloat16* __restrict__ K, int ldk,
    const __hip_bfloat16* __restrict__ VT,
    __hip_bfloat16* __restrict__ O) {
  __shared__ __align__(16) __hip_bfloat16 Ks[2][128 * 64];   // [j][d]
  __shared__ __align__(16) __hip_bfloat16 Vs[2][64 * 128];   // [d][j]
  __shared__ __align__(16) __hip_bfloat16 Ps[4][16 * 128];
  const int qt = blockIdx.x;
  const int bh = blockIdx.y;
  const int b = bh >> 4, h = bh & (NH - 1);
  const int tid = threadIdx.x, lane = tid & 63, wid = tid >> 6;
  const int frow = lane & 15, fg = lane >> 4;

  const __hip_bfloat16* Qb = Q + ((long)b * LL) * ldq + h * DKH;
  const __hip_bfloat16* Kb = K + ((long)b * LL) * ldk + h * DKH;
  const __hip_bfloat16* Vb = VT + (long)b * DM * LL + (long)(h * DKH) * LL;
  __hip_bfloat16* Ob = O + ((long)b * LL) * DM + h * DKH;

  auto stageKV = [&](int buf, int jt) {
    #pragma unroll
    for (int u = 0; u < 4; ++u) {
      const int R0 = (wid * 4 + u) * 8;
      const int row = R0 + (lane >> 3);
      const int cg = (lane & 7) ^ (row & 7);
      gload16(Kb + (long)(jt * 128 + row) * ldk + cg * 8, &Ks[buf][R0 * 64]);
    }
    #pragma unroll
    for (int u = 0; u < 4; ++u) {
      const int R0 = (wid * 4 + u) * 4;
      const int row = R0 + (lane >> 4);
      const int cg = (lane & 15) ^ (row & 7);
      gload16(Vb + (long)row * LL + jt * 128 + cg * 8, &Vs[buf][R0 * 128]);
    }
  };

  const int qrow = qt * 64 + wid * 16 + frow;
  s16x8 aq[2];
  #pragma unroll
  for (int s = 0; s < 2; ++s)
    aq[s] = *(const s16x8*)(Qb + (long)qrow * ldq + s * 32 + fg * 8);

  f32x4 o[4] = {};
  float m[4], l[4];
  #pragma unroll
  for (int j = 0; j < 4; ++j) { m[j] = -INFINITY; l[j] = 0.0f; }

  const int ntiles = CAUSAL ? ((qt >> 1) + 1) : (LL / 128);
  stageKV(0, 0);
  for (int jt = 0; jt < ntiles; ++jt) {
    const int cur = jt & 1;
    const bool more = (jt + 1 < ntiles);
    if (more) {
      stageKV(cur ^ 1, jt + 1);
      asm volatile("s_waitcnt vmcnt(8)" ::: "memory");
    } else {
      asm volatile("s_waitcnt vmcnt(0)" ::: "memory");
    }
    __builtin_amdgcn_s_barrier();
    asm volatile("" ::: "memory");

    f32x4 sa[8] = {};
    __builtin_amdgcn_s_setprio(1);
    #pragma unroll
    for (int s = 0; s < 2; ++s)
      #pragma unroll
      for (int nf = 0; nf < 8; ++nf) {
        const int jr = nf * 16 + frow;
        const s16x8 kf = *(const s16x8*)&Ks[cur][jr * 64 + (((s * 4 + fg) ^ (jr & 7)) * 8)];
        sa[nf] = __builtin_amdgcn_mfma_f32_16x16x32_bf16(aq[s], kf, sa[nf], 0, 0, 0);
      }
    __builtin_amdgcn_s_setprio(0);
    #pragma unroll
    for (int nf = 0; nf < 8; ++nf)
      #pragma unroll
      for (int j = 0; j < 4; ++j) {
        float v = sa[nf][j] * 0.125f;
        if (CAUSAL) {
          const int r = qt * 64 + wid * 16 + fg * 4 + j;
          const int c = jt * 128 + nf * 16 + frow;
          if (c > r) v = -1e30f;
        }
        sa[nf][j] = v;
      }

    float fs[4];
    #pragma unroll
    for (int j = 0; j < 4; ++j) {
      float v = sa[0][j];
      #pragma unroll
      for (int nf = 1; nf < 8; ++nf) v = fmaxf(v, sa[nf][j]);
      v = fmaxf(v, __shfl_xor(v, 1));
      v = fmaxf(v, __shfl_xor(v, 2));
      v = fmaxf(v, __shfl_xor(v, 4));
      v = fmaxf(v, __shfl_xor(v, 8));
      const float mn = fmaxf(m[j], v);
      fs[j] = __expf(m[j] - mn);
      m[j] = mn;
    }
    float rs[4] = {0.0f, 0.0f, 0.0f, 0.0f};
    #pragma unroll
    for (int nf = 0; nf < 8; ++nf)
      #pragma unroll
      for (int j = 0; j < 4; ++j) {
        const float p = __expf(sa[nf][j] - m[j]);
        sa[nf][j] = p;
        rs[j] += p;
      }
    #pragma unroll
    for (int j = 0; j < 4; ++j) {
      float v = rs[j];
      v += __shfl_xor(v, 1);
      v += __shfl_xor(v, 2);
      v += __shfl_xor(v, 4);
      v += __shfl_xor(v, 8);
      l[j] = l[j] * fs[j] + v;
      o[0][j] *= fs[j]; o[1][j] *= fs[j]; o[2][j] *= fs[j]; o[3][j] *= fs[j];
    }

    __hip_bfloat16* Pw = &Ps[wid][0];
    #pragma unroll
    for (int nf = 0; nf < 8; ++nf)
      #pragma unroll
      for (int j = 0; j < 4; ++j) {
        const int qr = fg * 4 + j;
        const int col = nf * 16 + frow;
        Pw[qr * 128 + (((col >> 3) ^ (qr & 7)) * 8) + (col & 7)] = __float2bfloat16(sa[nf][j]);
      }
    asm volatile("s_waitcnt lgkmcnt(0)" ::: "memory");

    __builtin_amdgcn_s_setprio(1);
    #pragma unroll
    for (int ks = 0; ks < 4; ++ks) {
      const s16x8 pa = *(const s16x8*)&Pw[frow * 128 + (((ks * 4 + fg) ^ (frow & 7)) * 8)];
      #pragma unroll
      for (int nf = 0; nf < 4; ++nf) {
        const int dr = nf * 16 + frow;
        const s16x8 vf = *(const s16x8*)&Vs[cur][dr * 128 + (((ks * 4 + fg) ^ (dr & 7)) * 8)];
        o[nf] = __builtin_amdgcn_mfma_f32_16x16x32_bf16(pa, vf, o[nf], 0, 0, 0);
      }
    }
    __builtin_amdgcn_s_setprio(0);
    asm volatile("s_waitcnt lgkmcnt(0)" ::: "memory");
    __builtin_amdgcn_s_barrier();
  }

  #pragma unroll
  for (int nf = 0; nf < 4; ++nf)
    #pragma unroll
    for (int j = 0; j < 4; ++j) {
      const int row = qt * 64 + wid * 16 + fg * 4 + j;
      const int col = nf * 16 + frow;
      Ob[(long)row * DM + col] = __float2bfloat16(o[nf][j] / l[j]);
    }
}

// ---------------------------------------------------------------- LN over single (pre-added) input (1-barrier)
__global__ __launch_bounds__(256) void add_ln1(
    const float* __restrict__ x,
    const float* __restrict__ g, const float* __restrict__ bta,
    float* __restrict__ out, __hip_bfloat16* __restrict__ obf) {
  __shared__ float redS[4], redQ[4];
  const int tid = threadIdx.x;
  const int lane = tid & 63, wid = tid >> 6;
  const size_t base = (size_t)blockIdx.x * DM;
  float v[4];
  float ss = 0.0f, sq = 0.0f;
  #pragma unroll
  for (int u = 0; u < 4; ++u) {
    v[u] = x[base + tid + u * 256];
    ss += v[u];
    sq += v[u] * v[u];
  }
  #pragma unroll
  for (int off = 1; off < 64; off <<= 1) {
    ss += __shfl_xor(ss, off);
    sq += __shfl_xor(sq, off);
  }
  if (lane == 0) { redS[wid] = ss; redQ[wid] = sq; }
  __syncthreads();
  const float tot = redS[0] + redS[1] + redS[2] + redS[3];
  const float totq = redQ[0] + redQ[1] + redQ[2] + redQ[3];
  const float mean = tot * (1.0f / DM);
  const float var = totq * (1.0f / DM) - mean * mean;
  const float rstd = rsqrtf(var + 1e-5f);
  #pragma unroll
  for (int u = 0; u < 4; ++u) {
    const int c = tid + u * 256;
    const float o = g[c] * (v[u] - mean) * rstd + bta[c];
    out[base + c] = o;
    obf[base + c] = __float2bfloat16(o);
  }
}

// ---------------------------------------------------------------- host helpers
template<int BM, int BN, int BK, int RELU, int OBF, int SWZ, int VTM, int BMAP, int NTC = 0>
static inline void launch_gemm(hipStream_t st, const __hip_bfloat16* A, const __hip_bfloat16* BT,
                               const float* bias, void* C, int M, int N, int K,
                               int lda, int ldb, int ldc,
                               const float* res = nullptr, __hip_bfloat16* obf2 = nullptr,
                               __hip_bfloat16* vt = nullptr, int vt_off = 0, long vt_stride = 0) {
  dim3 g(N / BN, M / BM);
  gemm_mfma<BM, BN, BK, RELU, OBF, SWZ, VTM, BMAP, NTC><<<g, 256, 0, st>>>(
      A, BT, bias, C, K, lda, ldb, ldc, res, obf2, vt, vt_off, vt_stride);
}

static inline void add_tjob(TJobs& J, int& total, const float* src, __hip_bfloat16* dst,
                            int K, int N, int nmat) {
  const int i = J.njobs++;
  J.src[i] = src; J.dst[i] = dst; J.K[i] = K; J.N[i] = N;
  J.tiles[i] = nmat * (N / 64) * (K / 64);
  total += J.tiles[i];
}

extern "C" void kernel_launch(void* const* d_in, const int* in_sizes, int n_in,
                              void* d_out, int out_size, void* d_ws, size_t ws_size,
                              hipStream_t stream) {
  (void)in_sizes; (void)n_in; (void)out_size; (void)ws_size;
  const int*   s          = (const int*)d_in[0];
  const int*   t          = (const int*)d_in[1];
  const float* emb_s_w    = (const float*)d_in[2];
  const float* emb_t_w    = (const float*)d_in[3];
  const float* enc_qkv_w  = (const float*)d_in[4];
  const float* enc_qkv_b  = (const float*)d_in[5];
  const float* enc_o_w    = (const float*)d_in[6];
  const float* enc_o_b    = (const float*)d_in[7];
  const float* enc_ln_w   = (const float*)d_in[8];
  const float* enc_ln_b   = (const float*)d_in[9];
  const float* enc_w1     = (const float*)d_in[10];
  const float* enc_b1     = (const float*)d_in[11];
  const float* enc_w2     = (const float*)d_in[12];
  const float* enc_b2     = (const float*)d_in[13];
  const float* dec_qkv1_w = (const float*)d_in[14];
  const float* dec_qkv1_b = (const float*)d_in[15];
  const float* dec_o1_w   = (const float*)d_in[16];
  const float* dec_o1_b   = (const float*)d_in[17];
  const float* dec_qkv2_w = (const float*)d_in[18];
  const float* dec_qkv2_b = (const float*)d_in[19];
  const float* dec_o2_w   = (const float*)d_in[20];
  const float* dec_o2_b   = (const float*)d_in[21];
  const float* dec_ln_w   = (const float*)d_in[22];
  const float* dec_ln_b   = (const float*)d_in[23];
  const float* dec_w1     = (const float*)d_in[24];
  const float* dec_b1     = (const float*)d_in[25];
  const float* dec_w2     = (const float*)d_in[26];
  const float* dec_b2     = (const float*)d_in[27];
  const float* out_w      = (const float*)d_in[28];
  const float* out_b      = (const float*)d_in[29];
  float* out = (float*)d_out;

  char* p = (char*)d_ws;
  auto alloc = [&](size_t bytes) {
    char* r = p; p += (bytes + 255) & ~(size_t)255; return (void*)r;
  };
  const size_t T = (size_t)BB * LL * DM;
  const size_t DD = (size_t)DM * DM, DF = (size_t)DM * DFF;
  float* e    = (float*)alloc(T * 4);
  float* dcur = (float*)alloc(T * 4);
  float* tmp  = (float*)alloc(T * 4);
  float* d1b  = (float*)alloc(T * 4);
  float* d2b  = (float*)alloc(T * 4);
  float* pet  = (float*)alloc((size_t)LL * DM * 4);
  __hip_bfloat16* e_bf    = (__hip_bfloat16*)alloc(T * 2);
  __hip_bfloat16* dcur_bf = (__hip_bfloat16*)alloc(T * 2);
  __hip_bfloat16* d1b_bf  = (__hip_bfloat16*)alloc(T * 2);
  __hip_bfloat16* d2b_bf  = (__hip_bfloat16*)alloc(T * 2);
  __hip_bfloat16* q_bf    = (__hip_bfloat16*)alloc(T * 2);
  __hip_bfloat16* qkv_bf  = (__hip_bfloat16*)alloc((size_t)BB * LL * 3 * DM * 2);
  __hip_bfloat16* ab_bf   = (__hip_bfloat16*)alloc(T * 2);
  __hip_bfloat16* hid_bf  = (__hip_bfloat16*)alloc((size_t)BB * LL * DFF * 2);
  __hip_bfloat16* VT      = (__hip_bfloat16*)alloc((size_t)BB * DM * LL * 2);
  __hip_bfloat16* WT      = (__hip_bfloat16*)alloc((size_t)VTOK * DM * 2);   // per-layer reuse + out_w
  __hip_bfloat16* WTq   = (__hip_bfloat16*)alloc(4 * DD * 2);
  __hip_bfloat16* WTkv  = (__hip_bfloat16*)alloc(8 * DD * 2);
  __hip_bfloat16* kvall = (__hip_bfloat16*)alloc((size_t)BB * LL * 8192 * 2);
  const long VT4S = (long)BB * DM * LL;
  __hip_bfloat16* VT4   = (__hip_bfloat16*)alloc(4 * VT4S * 2);

  const int M = BB * LL;

  pe_table_kernel<<<(LL * DM) / 256, 256, 0, stream>>>(pet);
  embed2_kernel<<<dim3((int)(T / 256), 2), 256, 0, stream>>>(
      s, t, emb_s_w, emb_t_w, pet, e, e_bf, dcur, dcur_bf);

  // ---- encoder ----
  for (int i = 0; i < NSL; ++i) {
    TJobs J{}; int tot = 0;
    add_tjob(J, tot, enc_qkv_w + (size_t)i * 3 * DD, WT,            DM, DM, 3);
    add_tjob(J, tot, enc_o_w   + (size_t)i * DD,     WT + 3 * DD,   DM, DM, 1);
    add_tjob(J, tot, enc_w1    + (size_t)i * DF,     WT + 4 * DD,   DM, DFF, 1);
    add_tjob(J, tot, enc_w2    + (size_t)i * DF,     WT + 4 * DD + DF, DFF, DM, 1);
    transpose_multi<<<tot, 256, 0, stream>>>(J);

    launch_gemm<64, 64, 128, 0, 1, 0, 1, 0>(stream, e_bf, WT,
                                            enc_qkv_b + (size_t)i * 3 * DM, qkv_bf,
                                            M, 3 * DM, DM, DM, DM, 3 * DM,
                                            nullptr, nullptr, VT, 2 * DM);
    flash_attn<0><<<dim3(LL / 64, BB * NH), 256, 0, stream>>>(
        qkv_bf, 3 * DM, qkv_bf + DM, 3 * DM, VT, ab_bf);
    launch_gemm<64, 32, 128, 0, 0, 0, 0, 0>(stream, ab_bf, WT + 3 * DD,
                                            enc_o_b + (size_t)i * DM, tmp,
                                            M, DM, DM, DM, DM, DM, e);
    add_ln1<<<M, 256, 0, stream>>>(tmp, enc_ln_w + (size_t)i * DM, enc_ln_b + (size_t)i * DM, e, e_bf);
    launch_gemm<128, 64, 64, 1, 1, 0, 0, 0>(stream, e_bf, WT + 4 * DD,
                                            enc_b1 + (size_t)i * DFF, hid_bf,
                                            M, DFF, DM, DM, DM, DFF);
    launch_gemm<64, 32, 128, 0, 0, 0, 0, 0>(stream, hid_bf, WT + 4 * DD + DF,
                                            enc_b2 + (size_t)i * DM, tmp,
                                            M, DM, DFF, DFF, DFF, DM, e);
    add_ln1<<<M, 256, 0, stream>>>(tmp, enc_ln_w + (size_t)i * DM, enc_ln_b + (size_t)i * DM, e, e_bf);
  }

  // ---- decoder cross-attn K/V batched across all 4 layers (e is final) ----
  {
    TJobs J{}; int tot = 0;
    for (int i = 0; i < NSL; ++i) {
      add_tjob(J, tot, dec_qkv2_w + (size_t)i * 3 * DD,      WTq  + (size_t)i * DD,     DM, DM, 1);
      add_tjob(J, tot, dec_qkv2_w + (size_t)i * 3 * DD + DD, WTkv + (size_t)i * 2 * DD, DM, DM, 2);
    }
    transpose_multi<<<tot, 256, 0, stream>>>(J);
    launch_gemm<128, 128, 32, 0, 1, 0, 2, 1>(stream, e_bf, WTkv, dec_qkv2_b, kvall,
                                             M, 8192, DM, DM, DM, 8192,
                                             nullptr, nullptr, VT4, 0, VT4S);
  }

  // ---- decoder ----
  for (int i = 0; i < NSL; ++i) {
    TJobs J{}; int tot = 0;
    add_tjob(J, tot, dec_qkv1_w + (size_t)i * 3 * DD, WT,              DM, DM, 3);
    add_tjob(J, tot, dec_o1_w   + (size_t)i * DD,     WT + 3 * DD,     DM, DM, 1);
    add_tjob(J, tot, dec_o2_w   + (size_t)i * DD,     WT + 4 * DD,     DM, DM, 1);
    add_tjob(J, tot, dec_w1     + (size_t)i * DF,     WT + 5 * DD,     DM, DFF, 1);
    add_tjob(J, tot, dec_w2     + (size_t)i * DF,     WT + 5 * DD + DF, DFF, DM, 1);
    transpose_multi<<<tot, 256, 0, stream>>>(J);

    launch_gemm<64, 64, 128, 0, 1, 0, 1, 0>(stream, dcur_bf, WT,
                                            dec_qkv1_b + (size_t)i * 3 * DM, qkv_bf,
                                            M, 3 * DM, DM, DM, DM, 3 * DM,
                                            nullptr, nullptr, VT, 2 * DM);
    flash_attn<1><<<dim3(LL / 64, BB * NH), 256, 0, stream>>>(
        qkv_bf, 3 * DM, qkv_bf + DM, 3 * DM, VT, ab_bf);
    launch_gemm<64, 32, 128, 0, 0, 0, 0, 0>(stream, ab_bf, WT + 3 * DD,
                                            dec_o1_b + (size_t)i * DM, tmp,
                                            M, DM, DM, DM, DM, DM, dcur);
    add_ln1<<<M, 256, 0, stream>>>(tmp, dec_ln_w + (size_t)i * DM, dec_ln_b + (size_t)i * DM, d1b, d1b_bf);

    launch_gemm<64, 32, 128, 0, 1, 0, 0, 0>(stream, d1b_bf, WTq + (size_t)i * DD,
                                            dec_qkv2_b + (size_t)i * 3 * DM, q_bf,
                                            M, DM, DM, DM, DM, DM);
    flash_attn<1><<<dim3(LL / 64, BB * NH), 256, 0, stream>>>(
        q_bf, DM, kvall + (size_t)2048 * i, 8192, VT4 + (size_t)i * VT4S, ab_bf);
    launch_gemm<64, 32, 128, 0, 0, 0, 0, 0>(stream, ab_bf, WT + 4 * DD,
                                            dec_o2_b + (size_t)i * DM, tmp,
                                            M, DM, DM, DM, DM, DM, d1b);
    add_ln1<<<M, 256, 0, stream>>>(tmp, dec_ln_w + (size_t)i * DM, dec_ln_b + (size_t)i * DM, d2b, d2b_bf);

    launch_gemm<128, 64, 64, 1, 1, 0, 0, 0>(stream, d2b_bf, WT + 5 * DD,
                                            dec_b1 + (size_t)i * DFF, hid_bf,
                                            M, DFF, DM, DM, DM, DFF);
    launch_gemm<64, 32, 128, 0, 0, 0, 0, 0>(stream, hid_bf, WT + 5 * DD + DF,
                                            dec_b2 + (size_t)i * DM, dcur,
                                            M, DM, DFF, DFF, DFF, DM, d2b, dcur_bf);
  }

  // ---- output projection (BN=128/BK=64, NTC coalesced NT stores) ----
  {
    TJobs J{}; int tot = 0;
    add_tjob(J, tot, out_w, WT, DM, VTOK, 1);
    transpose_multi<<<tot, 256, 0, stream>>>(J);
  }
  launch_gemm<128, 128, 64, 0, 0, 1, 0, 0, 1>(stream, dcur_bf, WT, out_b, out,
                                              M, VTOK, DM, DM, DM, VTOK);
}

// Round 19
// 1093.381 us; speedup vs baseline: 1.0120x; 1.0120x over previous
//
#include <hip/hip_runtime.h>
#include <hip/hip_bf16.h>
#include <math.h>

#define NSL 4
#define DM 1024
#define NH 16
#define DKH 64
#define DFF 4096
#define BB 2
#define LL 512
#define VTOK 32000

typedef short s16x8 __attribute__((ext_vector_type(8)));
typedef float f32x4 __attribute__((ext_vector_type(4)));

__device__ __forceinline__ void gload16(const void* g, void* l) {
  __builtin_amdgcn_global_load_lds((__attribute__((address_space(1))) void*)g,
                                   (__attribute__((address_space(3))) void*)l, 16, 0, 0);
}

// ---------------------------------------------------------------- PE table (pos,dim) -> final additive value
__global__ __launch_bounds__(256) void pe_table_kernel(float* __restrict__ pet) {
  const int idx = blockIdx.x * 256 + threadIdx.x;   // LL*DM
  const int dim = idx & (DM - 1);
  const int pos = idx >> 10;
  const float denum = powf(10000.0f, (2.0f * (float)dim) / (float)DM);
  const float pe = (float)pos / denum;
  pet[idx] = (dim & 1) ? cosf(pe) : (1.0f + sinf(pe));
}

// ---------------------------------------------------------------- embedding (both streams, z-batched, PE table)
__global__ __launch_bounds__(256) void embed2_kernel(
    const int* __restrict__ toks, const int* __restrict__ tokt,
    const float* __restrict__ ws, const float* __restrict__ wt,
    const float* __restrict__ pet,
    float* __restrict__ eo, __hip_bfloat16* __restrict__ eobf,
    float* __restrict__ dco, __hip_bfloat16* __restrict__ dcobf) {
  const int which = blockIdx.y;
  const int* tok = which ? tokt : toks;
  const float* w = which ? wt : ws;
  float* o = which ? dco : eo;
  __hip_bfloat16* obf = which ? dcobf : eobf;
  const int idx = blockIdx.x * 256 + threadIdx.x;   // BB*LL*DM
  const int dim = idx & (DM - 1);
  const int pos = (idx >> 10) & (LL - 1);
  const int b   = idx >> 19;
  const int token = tok[b * LL + pos];
  const float r = w[(size_t)token * DM + dim] + pet[pos * DM + dim];
  o[idx] = r;
  obf[idx] = __float2bfloat16(r);
}

// ---------------------------------------------------------------- multi-job weight transpose (up to 10 jobs)
struct TJobs {
  const float* src[10];
  __hip_bfloat16* dst[10];
  int K[10];
  int N[10];
  int tiles[10];
  int njobs;
};

__global__ __launch_bounds__(256) void transpose_multi(TJobs jobs) {
  __shared__ float tb[64][65];
  int t = blockIdx.x;
  int ji = 0;
  while (t >= jobs.tiles[ji]) { t -= jobs.tiles[ji]; ++ji; }
  const int K = jobs.K[ji], N = jobs.N[ji];
  const int tpx = N >> 6;
  const int tpm = tpx * (K >> 6);
  const int mat = t / tpm;
  const int t2 = t - mat * tpm;
  const float* src = jobs.src[ji] + (long)mat * K * N;
  __hip_bfloat16* dst = jobs.dst[ji] + (long)mat * K * N;
  const int n0 = (t2 % tpx) * 64, k0 = (t2 / tpx) * 64;
  const int lc = (threadIdx.x & 15) * 4;
  const int lr = threadIdx.x >> 4;
  #pragma unroll
  for (int u = 0; u < 4; ++u) {
    const int r = lr + u * 16;
    const float4 v = *(const float4*)(src + (long)(k0 + r) * N + n0 + lc);
    tb[r][lc + 0] = v.x; tb[r][lc + 1] = v.y; tb[r][lc + 2] = v.z; tb[r][lc + 3] = v.w;
  }
  __syncthreads();
  #pragma unroll
  for (int u = 0; u < 4; ++u) {
    const int r = lr + u * 16;
    ushort4 o;
    __hip_bfloat16 h0 = __float2bfloat16(tb[lc + 0][r]);
    __hip_bfloat16 h1 = __float2bfloat16(tb[lc + 1][r]);
    __hip_bfloat16 h2 = __float2bfloat16(tb[lc + 2][r]);
    __hip_bfloat16 h3 = __float2bfloat16(tb[lc + 3][r]);
    o.x = *(unsigned short*)&h0; o.y = *(unsigned short*)&h1;
    o.z = *(unsigned short*)&h2; o.w = *(unsigned short*)&h3;
    *(ushort4*)(dst + (long)(n0 + r) * K + k0 + lc) = o;
  }
}

// ---------------------------------------------------------------- MFMA GEMM (counted-vmcnt dbuf pipeline)
// C[M,N] = A[M,K] @ BT[N,K]^T + bias (+res) ; A,BT bf16 k-contiguous.
// VTM=0 none; 1: cols>=vt_off -> vt[b][d][j]; 2: mega-kv V halves -> vt+(bn>>11)*vt_stride.
// BMAP=1: bias indexed as dec_qkv2_b kv-stack. NTC=1: LDS-staged coalesced nontemporal fp32 C.
template<int BM, int BN, int BK, int RELU, int OBF, int SWZ, int VTM, int BMAP, int NTC>
__global__ __launch_bounds__(256, 2) void gemm_mfma(
    const __hip_bfloat16* __restrict__ A, const __hip_bfloat16* __restrict__ BT,
    const float* __restrict__ bias, void* __restrict__ Cout,
    int K, int lda, int ldb, int ldc,
    const float* __restrict__ res, __hip_bfloat16* __restrict__ obf2,
    __hip_bfloat16* __restrict__ vt, int vt_off, long vt_stride) {
  constexpr int WR = BM / 2, WC = BN / 2;
  constexpr int MF = WR / 16, NF = WC / 16;
  constexpr int CHK = BK / 8;            // 16B chunks per row
  constexpr int RPC = 64 / CHK;          // rows per wave-call
  constexpr int ACALLS = BM / RPC / 4, BCALLS = BN / RPC / 4;
  constexpr int NLOADS = ACALLS + BCALLS;
  constexpr int KSUB = BK / 32;          // MFMA k sub-steps per tile
  constexpr int ABUF = BM * BK, BBUF = BN * BK;
  constexpr int STAGE_BYTES = 2 * (ABUF + BBUF) * 2;
  constexpr int TT_BYTES = (VTM != 0) ? (BM * BN * 2) : 0;
  constexpr int CF_BYTES = NTC ? ((BM / 2) * BN * 4) : 0;   // 64-row fp32 staging
  constexpr int SMEM_A = STAGE_BYTES > TT_BYTES ? STAGE_BYTES : TT_BYTES;
  constexpr int SMEM_BYTES = SMEM_A > CF_BYTES ? SMEM_A : CF_BYTES;
  __shared__ __align__(16) char smem[SMEM_BYTES];
  __hip_bfloat16* As = (__hip_bfloat16*)smem;                          // [2][ABUF]
  __hip_bfloat16* Bs = (__hip_bfloat16*)(smem + (size_t)2 * ABUF * 2); // [2][BBUF]
  unsigned short* TT = (unsigned short*)smem;   // epilogue reuse

  int bx = blockIdx.x, by = blockIdx.y;
  if (SWZ) {
    const int gx = gridDim.x;
    const int nwg = gx * gridDim.y;     // caller guarantees %8==0
    const int id = by * gx + bx;
    const int qq = nwg >> 3;
    const int swz = (id & 7) * qq + (id >> 3);
    bx = swz % gx; by = swz / gx;
  }
  const int bm = by * BM, bn = bx * BN;
  const int tid = threadIdx.x, lane = tid & 63, wid = tid >> 6;
  const int wr = (wid >> 1) * WR, wc = (wid & 1) * WC;
  const int frow = lane & 15, fkc = lane >> 4;

  // XOR chunk swizzle (pre-swizzled SOURCE + same rule on read — rule #21)
  auto swz_chk = [](int c, int r) {
    if (BK == 32)      return c ^ ((r >> 1) & 3);
    else if (BK == 64) return c ^ (r & 7);
    else               return c ^ (r & 15);
  };

  const int s_row = lane / CHK;          // row within call
  const int s_chk = lane % CHK;

  auto stageAB = [&](int buf, int k0) {
    #pragma unroll
    for (int c = 0; c < ACALLS; ++c) {
      const int R0 = (wid * ACALLS + c) * RPC;
      const int row = R0 + s_row;
      gload16(A + (long)(bm + row) * lda + k0 + swz_chk(s_chk, row) * 8,
              As + buf * ABUF + R0 * BK);
    }
    #pragma unroll
    for (int c = 0; c < BCALLS; ++c) {
      const int R0 = (wid * BCALLS + c) * RPC;
      const int row = R0 + s_row;
      gload16(BT + (long)(bn + row) * ldb + k0 + swz_chk(s_chk, row) * 8,
              Bs + buf * BBUF + R0 * BK);
    }
  };

  f32x4 acc[MF][NF] = {};
  const int nt = K / BK;
  stageAB(0, 0);
  for (int t = 0; t < nt; ++t) {
    const int cur = t & 1;
    const bool more = (t + 1 < nt);
    if (more) {
      stageAB(cur ^ 1, (t + 1) * BK);                    // next tile stays in flight
      asm volatile("s_waitcnt vmcnt(%0)" :: "n"(NLOADS) : "memory");  // oldest = tile t landed
    } else {
      asm volatile("s_waitcnt vmcnt(0)" ::: "memory");
    }
    __builtin_amdgcn_s_barrier();                        // tile t globally visible
    asm volatile("" ::: "memory");
    #pragma unroll
    for (int s = 0; s < KSUB; ++s) {
      s16x8 af[MF], bfr[NF];
      #pragma unroll
      for (int mm = 0; mm < MF; ++mm) {
        const int r = wr + mm * 16 + frow;
        af[mm] = *(const s16x8*)&As[cur * ABUF + r * BK + swz_chk(s * 4 + fkc, r) * 8];
      }
      #pragma unroll
      for (int nn = 0; nn < NF; ++nn) {
        const int r = wc + nn * 16 + frow;
        bfr[nn] = *(const s16x8*)&Bs[cur * BBUF + r * BK + swz_chk(s * 4 + fkc, r) * 8];
      }
      #pragma unroll
      for (int mm = 0; mm < MF; ++mm)
        #pragma unroll
        for (int nn = 0; nn < NF; ++nn)
          acc[mm][nn] = __builtin_amdgcn_mfma_f32_16x16x32_bf16(af[mm], bfr[nn], acc[mm][nn], 0, 0, 0);
    }
    asm volatile("s_waitcnt lgkmcnt(0)" ::: "memory");   // my frag reads complete
    __builtin_amdgcn_s_barrier();                        // buf cur may be overwritten next iter
  }

  if (NTC) {
    // LDS-staged coalesced nontemporal C write (full 128B lines, no L3 pollution)
    float* CF = (float*)smem;                            // [BM/2][BN] fp32
    #pragma unroll
    for (int half = 0; half < 2; ++half) {
      __syncthreads();                                   // protect CF reuse
      if ((wid >> 1) == half) {
        #pragma unroll
        for (int mm = 0; mm < MF; ++mm)
          #pragma unroll
          for (int nn = 0; nn < NF; ++nn) {
            const int col = wc + nn * 16 + frow;
            const float bs = bias[bn + col];
            #pragma unroll
            for (int j = 0; j < 4; ++j)
              CF[(mm * 16 + fkc * 4 + j) * BN + col] = acc[mm][nn][j] + bs;
          }
      }
      __syncthreads();
      constexpr int NPASS = (BM / 2) * BN / 4 / 256;
      #pragma unroll
      for (int ps = 0; ps < NPASS; ++ps) {
        const int idx = tid * 4 + ps * 1024;
        const int row = idx / BN, col = idx % BN;
        const f32x4 v = *(const f32x4*)&CF[row * BN + col];
        __builtin_nontemporal_store(
            v, (f32x4*)((float*)Cout + (long)(bm + half * (BM / 2) + row) * ldc + bn + col));
      }
    }
    return;
  }

  bool vt_blk = false;
  if (VTM == 1) vt_blk = (bn >= vt_off);
  if (VTM == 2) vt_blk = (((bn >> 10) & 1) == 1);

  #pragma unroll
  for (int mm = 0; mm < MF; ++mm)
    #pragma unroll
    for (int nn = 0; nn < NF; ++nn) {
      const int row0 = bm + wr + mm * 16 + fkc * 4;
      const int col  = bn + wc + nn * 16 + frow;
      float bs;
      if (BMAP) bs = bias[(col >> 11) * 3 * DM + DM + (col & 2047)];
      else      bs = bias[col];
      float vv[4];
      #pragma unroll
      for (int j = 0; j < 4; ++j) {
        float v = acc[mm][nn][j] + bs;
        if (RELU) v = fmaxf(v, 0.0f);
        const long ci = (long)(row0 + j) * ldc + col;
        if (res) v += res[ci];
        if (OBF) ((__hip_bfloat16*)Cout)[ci] = __float2bfloat16(v);
        else     ((float*)Cout)[ci] = v;
        if (obf2) obf2[ci] = __float2bfloat16(v);
        vv[j] = v;
      }
      if (VTM != 0 && vt_blk) {
        const int dl  = wc + nn * 16 + frow;
        const int jl0 = (wr + mm * 16 + fkc * 4) ^ ((dl & 7) << 3);
        ushort4 pk;
        __hip_bfloat16 h0 = __float2bfloat16(vv[0]);
        __hip_bfloat16 h1 = __float2bfloat16(vv[1]);
        __hip_bfloat16 h2 = __float2bfloat16(vv[2]);
        __hip_bfloat16 h3 = __float2bfloat16(vv[3]);
        pk.x = *(unsigned short*)&h0; pk.y = *(unsigned short*)&h1;
        pk.z = *(unsigned short*)&h2; pk.w = *(unsigned short*)&h3;
        *(ushort4*)&TT[dl * BM + jl0] = pk;
      }
    }

  if (VTM != 0 && vt_blk) {
    __syncthreads();
    constexpr int TPR = BM / 8;
    constexpr int RPP = 256 / TPR;
    constexpr int NP  = BN / RPP;
    const int jj = (tid % TPR) * 8;
    const int b = bm >> 9;
    const int jbase = bm & (LL - 1);
    const __hip_bfloat16* vtp;
    int dg0;
    if (VTM == 2) {
      vtp = vt + (long)(bn >> 11) * vt_stride;
      dg0 = bn & 1023;
    } else {
      vtp = vt;
      dg0 = bn - vt_off;
    }
    #pragma unroll
    for (int u = 0; u < NP; ++u) {
      const int dl = (tid / TPR) + u * RPP;
      const s16x8 val = *(const s16x8*)&TT[dl * BM + (jj ^ ((dl & 7) << 3))];
      *(s16x8*)((__hip_bfloat16*)vtp + ((long)(b * DM + dg0 + dl)) * LL + jbase + jj) = val;
    }
  }
}

// ---------------------------------------------------------------- flash attention (KVBLK=128, counted-vmcnt dbuf, T5)
template<int CAUSAL>
__global__ __launch_bounds__(256) void flash_attn(
    const __hip_bfloat16* __restrict__ Q, int ldq,
    const __hip_bfloat16* __restrict__ K, int ldk,
    const __hip_bfloat16* __restrict__ VT,
    __hip_bfloat16* __restrict__ O) {
  __shared__ __align__(16) __hip_bfloat16 Ks[2][128 * 64];   // [j][d]
  __shared__ __align__(16) __hip_bfloat16 Vs[2][64 * 128];   // [d][j]
  __shared__ __align__(16) __hip_bfloat16 Ps[4][16 * 128];
  const int qt = blockIdx.x;
  const int bh = blockIdx.y;
  const int b = bh >> 4, h = bh & (NH - 1);
  const int tid = threadIdx.x, lane = tid & 63, wid = tid >> 6;
  const int frow = lane & 15, fg = lane >> 4;

  const __hip_bfloat16* Qb = Q + ((long)b * LL) * ldq + h * DKH;
  const __hip_bfloat16* Kb = K + ((long)b * LL) * ldk + h * DKH;
  const __hip_bfloat16* Vb = VT + (long)b * DM * LL + (long)(h * DKH) * LL;
  __hip_bfloat16* Ob = O + ((long)b * LL) * DM + h * DKH;

  auto stageKV = [&](int buf, int jt) {
    #pragma unroll
    for (int u = 0; u < 4; ++u) {
      const int R0 = (wid * 4 + u) * 8;
      const int row = R0 + (lane >> 3);
      const int cg = (lane & 7) ^ (row & 7);
      gload16(Kb + (long)(jt * 128 + row) * ldk + cg * 8, &Ks[buf][R0 * 64]);
    }
    #pragma unroll
    for (int u = 0; u < 4; ++u) {
      const int R0 = (wid * 4 + u) * 4;
      const int row = R0 + (lane >> 4);
      const int cg = (lane & 15) ^ (row & 7);
      gload16(Vb + (long)row * LL + jt * 128 + cg * 8, &Vs[buf][R0 * 128]);
    }
  };

  const int qrow = qt * 64 + wid * 16 + frow;
  s16x8 aq[2];
  #pragma unroll
  for (int s = 0; s < 2; ++s)
    aq[s] = *(const s16x8*)(Qb + (long)qrow * ldq + s * 32 + fg * 8);

  f32x4 o[4] = {};
  float m[4], l[4];
  #pragma unroll
  for (int j = 0; j < 4; ++j) { m[j] = -INFINITY; l[j] = 0.0f; }

  const int ntiles = CAUSAL ? ((qt >> 1) + 1) : (LL / 128);
  stageKV(0, 0);
  for (int jt = 0; jt < ntiles; ++jt) {
    const int cur = jt & 1;
    const bool more = (jt + 1 < ntiles);
    if (more) {
      stageKV(cur ^ 1, jt + 1);
      asm volatile("s_waitcnt vmcnt(8)" ::: "memory");
    } else {
      asm volatile("s_waitcnt vmcnt(0)" ::: "memory");
    }
    __builtin_amdgcn_s_barrier();
    asm volatile("" ::: "memory");

    f32x4 sa[8] = {};
    __builtin_amdgcn_s_setprio(1);
    #pragma unroll
    for (int s = 0; s < 2; ++s)
      #pragma unroll
      for (int nf = 0; nf < 8; ++nf) {
        const int jr = nf * 16 + frow;
        const s16x8 kf = *(const s16x8*)&Ks[cur][jr * 64 + (((s * 4 + fg) ^ (jr & 7)) * 8)];
        sa[nf] = __builtin_amdgcn_mfma_f32_16x16x32_bf16(aq[s], kf, sa[nf], 0, 0, 0);
      }
    __builtin_amdgcn_s_setprio(0);
    #pragma unroll
    for (int nf = 0; nf < 8; ++nf)
      #pragma unroll
      for (int j = 0; j < 4; ++j) {
        float v = sa[nf][j] * 0.125f;
        if (CAUSAL) {
          const int r = qt * 64 + wid * 16 + fg * 4 + j;
          const int c = jt * 128 + nf * 16 + frow;
          if (c > r) v = -1e30f;
        }
        sa[nf][j] = v;
      }

    float fs[4];
    #pragma unroll
    for (int j = 0; j < 4; ++j) {
      float v = sa[0][j];
      #pragma unroll
      for (int nf = 1; nf < 8; ++nf) v = fmaxf(v, sa[nf][j]);
      v = fmaxf(v, __shfl_xor(v, 1));
      v = fmaxf(v, __shfl_xor(v, 2));
      v = fmaxf(v, __shfl_xor(v, 4));
      v = fmaxf(v, __shfl_xor(v, 8));
      const float mn = fmaxf(m[j], v);
      fs[j] = __expf(m[j] - mn);
      m[j] = mn;
    }
    float rs[4] = {0.0f, 0.0f, 0.0f, 0.0f};
    #pragma unroll
    for (int nf = 0; nf < 8; ++nf)
      #pragma unroll
      for (int j = 0; j < 4; ++j) {
        const float p = __expf(sa[nf][j] - m[j]);
        sa[nf][j] = p;
        rs[j] += p;
      }
    #pragma unroll
    for (int j = 0; j < 4; ++j) {
      float v = rs[j];
      v += __shfl_xor(v, 1);
      v += __shfl_xor(v, 2);
      v += __shfl_xor(v, 4);
      v += __shfl_xor(v, 8);
      l[j] = l[j] * fs[j] + v;
      o[0][j] *= fs[j]; o[1][j] *= fs[j]; o[2][j] *= fs[j]; o[3][j] *= fs[j];
    }

    __hip_bfloat16* Pw = &Ps[wid][0];
    #pragma unroll
    for (int nf = 0; nf < 8; ++nf)
      #pragma unroll
      for (int j = 0; j < 4; ++j) {
        const int qr = fg * 4 + j;
        const int col = nf * 16 + frow;
        Pw[qr * 128 + (((col >> 3) ^ (qr & 7)) * 8) + (col & 7)] = __float2bfloat16(sa[nf][j]);
      }
    asm volatile("s_waitcnt lgkmcnt(0)" ::: "memory");

    __builtin_amdgcn_s_setprio(1);
    #pragma unroll
    for (int ks = 0; ks < 4; ++ks) {
      const s16x8 pa = *(const s16x8*)&Pw[frow * 128 + (((ks * 4 + fg) ^ (frow & 7)) * 8)];
      #pragma unroll
      for (int nf = 0; nf < 4; ++nf) {
        const int dr = nf * 16 + frow;
        const s16x8 vf = *(const s16x8*)&Vs[cur][dr * 128 + (((ks * 4 + fg) ^ (dr & 7)) * 8)];
        o[nf] = __builtin_amdgcn_mfma_f32_16x16x32_bf16(pa, vf, o[nf], 0, 0, 0);
      }
    }
    __builtin_amdgcn_s_setprio(0);
    asm volatile("s_waitcnt lgkmcnt(0)" ::: "memory");
    __builtin_amdgcn_s_barrier();
  }

  #pragma unroll
  for (int nf = 0; nf < 4; ++nf)
    #pragma unroll
    for (int j = 0; j < 4; ++j) {
      const int row = qt * 64 + wid * 16 + fg * 4 + j;
      const int col = nf * 16 + frow;
      Ob[(long)row * DM + col] = __float2bfloat16(o[nf][j] / l[j]);
    }
}

// ---------------------------------------------------------------- LN over single (pre-added) input (1-barrier)
__global__ __launch_bounds__(256) void add_ln1(
    const float* __restrict__ x,
    const float* __restrict__ g, const float* __restrict__ bta,
    float* __restrict__ out, __hip_bfloat16* __restrict__ obf) {
  __shared__ float redS[4], redQ[4];
  const int tid = threadIdx.x;
  const int lane = tid & 63, wid = tid >> 6;
  const size_t base = (size_t)blockIdx.x * DM;
  float v[4];
  float ss = 0.0f, sq = 0.0f;
  #pragma unroll
  for (int u = 0; u < 4; ++u) {
    v[u] = x[base + tid + u * 256];
    ss += v[u];
    sq += v[u] * v[u];
  }
  #pragma unroll
  for (int off = 1; off < 64; off <<= 1) {
    ss += __shfl_xor(ss, off);
    sq += __shfl_xor(sq, off);
  }
  if (lane == 0) { redS[wid] = ss; redQ[wid] = sq; }
  __syncthreads();
  const float tot = redS[0] + redS[1] + redS[2] + redS[3];
  const float totq = redQ[0] + redQ[1] + redQ[2] + redQ[3];
  const float mean = tot * (1.0f / DM);
  const float var = totq * (1.0f / DM) - mean * mean;
  const float rstd = rsqrtf(var + 1e-5f);
  #pragma unroll
  for (int u = 0; u < 4; ++u) {
    const int c = tid + u * 256;
    const float o = g[c] * (v[u] - mean) * rstd + bta[c];
    out[base + c] = o;
    obf[base + c] = __float2bfloat16(o);
  }
}

// ---------------------------------------------------------------- host helpers
template<int BM, int BN, int BK, int RELU, int OBF, int SWZ, int VTM, int BMAP, int NTC = 0>
static inline void launch_gemm(hipStream_t st, const __hip_bfloat16* A, const __hip_bfloat16* BT,
                               const float* bias, void* C, int M, int N, int K,
                               int lda, int ldb, int ldc,
                               const float* res = nullptr, __hip_bfloat16* obf2 = nullptr,
                               __hip_bfloat16* vt = nullptr, int vt_off = 0, long vt_stride = 0) {
  dim3 g(N / BN, M / BM);
  gemm_mfma<BM, BN, BK, RELU, OBF, SWZ, VTM, BMAP, NTC><<<g, 256, 0, st>>>(
      A, BT, bias, C, K, lda, ldb, ldc, res, obf2, vt, vt_off, vt_stride);
}

static inline void add_tjob(TJobs& J, int& total, const float* src, __hip_bfloat16* dst,
                            int K, int N, int nmat) {
  const int i = J.njobs++;
  J.src[i] = src; J.dst[i] = dst; J.K[i] = K; J.N[i] = N;
  J.tiles[i] = nmat * (N / 64) * (K / 64);
  total += J.tiles[i];
}

extern "C" void kernel_launch(void* const* d_in, const int* in_sizes, int n_in,
                              void* d_out, int out_size, void* d_ws, size_t ws_size,
                              hipStream_t stream) {
  (void)in_sizes; (void)n_in; (void)out_size; (void)ws_size;
  const int*   s          = (const int*)d_in[0];
  const int*   t          = (const int*)d_in[1];
  const float* emb_s_w    = (const float*)d_in[2];
  const float* emb_t_w    = (const float*)d_in[3];
  const float* enc_qkv_w  = (const float*)d_in[4];
  const float* enc_qkv_b  = (const float*)d_in[5];
  const float* enc_o_w    = (const float*)d_in[6];
  const float* enc_o_b    = (const float*)d_in[7];
  const float* enc_ln_w   = (const float*)d_in[8];
  const float* enc_ln_b   = (const float*)d_in[9];
  const float* enc_w1     = (const float*)d_in[10];
  const float* enc_b1     = (const float*)d_in[11];
  const float* enc_w2     = (const float*)d_in[12];
  const float* enc_b2     = (const float*)d_in[13];
  const float* dec_qkv1_w = (const float*)d_in[14];
  const float* dec_qkv1_b = (const float*)d_in[15];
  const float* dec_o1_w   = (const float*)d_in[16];
  const float* dec_o1_b   = (const float*)d_in[17];
  const float* dec_qkv2_w = (const float*)d_in[18];
  const float* dec_qkv2_b = (const float*)d_in[19];
  const float* dec_o2_w   = (const float*)d_in[20];
  const float* dec_o2_b   = (const float*)d_in[21];
  const float* dec_ln_w   = (const float*)d_in[22];
  const float* dec_ln_b   = (const float*)d_in[23];
  const float* dec_w1     = (const float*)d_in[24];
  const float* dec_b1     = (const float*)d_in[25];
  const float* dec_w2     = (const float*)d_in[26];
  const float* dec_b2     = (const float*)d_in[27];
  const float* out_w      = (const float*)d_in[28];
  const float* out_b      = (const float*)d_in[29];
  float* out = (float*)d_out;

  char* p = (char*)d_ws;
  auto alloc = [&](size_t bytes) {
    char* r = p; p += (bytes + 255) & ~(size_t)255; return (void*)r;
  };
  const size_t T = (size_t)BB * LL * DM;
  const size_t DD = (size_t)DM * DM, DF = (size_t)DM * DFF;
  float* e    = (float*)alloc(T * 4);
  float* dcur = (float*)alloc(T * 4);
  float* tmp  = (float*)alloc(T * 4);
  float* d1b  = (float*)alloc(T * 4);
  float* d2b  = (float*)alloc(T * 4);
  float* pet  = (float*)alloc((size_t)LL * DM * 4);
  __hip_bfloat16* e_bf    = (__hip_bfloat16*)alloc(T * 2);
  __hip_bfloat16* dcur_bf = (__hip_bfloat16*)alloc(T * 2);
  __hip_bfloat16* d1b_bf  = (__hip_bfloat16*)alloc(T * 2);
  __hip_bfloat16* d2b_bf  = (__hip_bfloat16*)alloc(T * 2);
  __hip_bfloat16* q_bf    = (__hip_bfloat16*)alloc(T * 2);
  __hip_bfloat16* qkv_bf  = (__hip_bfloat16*)alloc((size_t)BB * LL * 3 * DM * 2);
  __hip_bfloat16* ab_bf   = (__hip_bfloat16*)alloc(T * 2);
  __hip_bfloat16* hid_bf  = (__hip_bfloat16*)alloc((size_t)BB * LL * DFF * 2);
  __hip_bfloat16* VT      = (__hip_bfloat16*)alloc((size_t)BB * DM * LL * 2);
  __hip_bfloat16* WT      = (__hip_bfloat16*)alloc((size_t)VTOK * DM * 2);   // 2-layer parity reuse + out_w
  __hip_bfloat16* WTq   = (__hip_bfloat16*)alloc(4 * DD * 2);
  __hip_bfloat16* WTkv  = (__hip_bfloat16*)alloc(8 * DD * 2);
  __hip_bfloat16* kvall = (__hip_bfloat16*)alloc((size_t)BB * LL * 8192 * 2);
  const long VT4S = (long)BB * DM * LL;
  __hip_bfloat16* VT4   = (__hip_bfloat16*)alloc(4 * VT4S * 2);

  const int M = BB * LL;
  const size_t LENC = 4 * DD + 2 * DF;   // per-layer transposed enc weights (elems)
  const size_t LDEC = 5 * DD + 2 * DF;   // per-layer transposed dec weights

  pe_table_kernel<<<(LL * DM) / 256, 256, 0, stream>>>(pet);
  embed2_kernel<<<dim3((int)(T / 256), 2), 256, 0, stream>>>(
      s, t, emb_s_w, emb_t_w, pet, e, e_bf, dcur, dcur_bf);

  // ---- encoder (transposes batched 2 layers at a time; working set ~48MB << L3) ----
  for (int i = 0; i < NSL; ++i) {
    if ((i & 1) == 0) {
      TJobs J{}; int tot = 0;
      for (int l = i; l < i + 2 && l < NSL; ++l) {
        __hip_bfloat16* base = WT + (size_t)(l & 1) * LENC;
        add_tjob(J, tot, enc_qkv_w + (size_t)l * 3 * DD, base,            DM, DM, 3);
        add_tjob(J, tot, enc_o_w   + (size_t)l * DD,     base + 3 * DD,   DM, DM, 1);
        add_tjob(J, tot, enc_w1    + (size_t)l * DF,     base + 4 * DD,   DM, DFF, 1);
        add_tjob(J, tot, enc_w2    + (size_t)l * DF,     base + 4 * DD + DF, DFF, DM, 1);
      }
      transpose_multi<<<tot, 256, 0, stream>>>(J);
    }
    __hip_bfloat16* base = WT + (size_t)(i & 1) * LENC;

    launch_gemm<64, 64, 128, 0, 1, 0, 1, 0>(stream, e_bf, base,
                                            enc_qkv_b + (size_t)i * 3 * DM, qkv_bf,
                                            M, 3 * DM, DM, DM, DM, 3 * DM,
                                            nullptr, nullptr, VT, 2 * DM);
    flash_attn<0><<<dim3(LL / 64, BB * NH), 256, 0, stream>>>(
        qkv_bf, 3 * DM, qkv_bf + DM, 3 * DM, VT, ab_bf);
    launch_gemm<64, 32, 128, 0, 0, 0, 0, 0>(stream, ab_bf, base + 3 * DD,
                                            enc_o_b + (size_t)i * DM, tmp,
                                            M, DM, DM, DM, DM, DM, e);
    add_ln1<<<M, 256, 0, stream>>>(tmp, enc_ln_w + (size_t)i * DM, enc_ln_b + (size_t)i * DM, e, e_bf);
    launch_gemm<128, 64, 64, 1, 1, 0, 0, 0>(stream, e_bf, base + 4 * DD,
                                            enc_b1 + (size_t)i * DFF, hid_bf,
                                            M, DFF, DM, DM, DM, DFF);
    launch_gemm<64, 32, 128, 0, 0, 0, 0, 0>(stream, hid_bf, base + 4 * DD + DF,
                                            enc_b2 + (size_t)i * DM, tmp,
                                            M, DM, DFF, DFF, DFF, DM, e);
    add_ln1<<<M, 256, 0, stream>>>(tmp, enc_ln_w + (size_t)i * DM, enc_ln_b + (size_t)i * DM, e, e_bf);
  }

  // ---- decoder cross-attn K/V batched across all 4 layers (e is final) ----
  {
    TJobs J{}; int tot = 0;
    for (int i = 0; i < NSL; ++i) {
      add_tjob(J, tot, dec_qkv2_w + (size_t)i * 3 * DD,      WTq  + (size_t)i * DD,     DM, DM, 1);
      add_tjob(J, tot, dec_qkv2_w + (size_t)i * 3 * DD + DD, WTkv + (size_t)i * 2 * DD, DM, DM, 2);
    }
    transpose_multi<<<tot, 256, 0, stream>>>(J);
    launch_gemm<128, 128, 32, 0, 1, 0, 2, 1>(stream, e_bf, WTkv, dec_qkv2_b, kvall,
                                             M, 8192, DM, DM, DM, 8192,
                                             nullptr, nullptr, VT4, 0, VT4S);
  }

  // ---- decoder (transposes batched 2 layers at a time) ----
  for (int i = 0; i < NSL; ++i) {
    if ((i & 1) == 0) {
      TJobs J{}; int tot = 0;
      for (int l = i; l < i + 2 && l < NSL; ++l) {
        __hip_bfloat16* base = WT + (size_t)(l & 1) * LDEC;
        add_tjob(J, tot, dec_qkv1_w + (size_t)l * 3 * DD, base,              DM, DM, 3);
        add_tjob(J, tot, dec_o1_w   + (size_t)l * DD,     base + 3 * DD,     DM, DM, 1);
        add_tjob(J, tot, dec_o2_w   + (size_t)l * DD,     base + 4 * DD,     DM, DM, 1);
        add_tjob(J, tot, dec_w1     + (size_t)l * DF,     base + 5 * DD,     DM, DFF, 1);
        add_tjob(J, tot, dec_w2     + (size_t)l * DF,     base + 5 * DD + DF, DFF, DM, 1);
      }
      transpose_multi<<<tot, 256, 0, stream>>>(J);
    }
    __hip_bfloat16* base = WT + (size_t)(i & 1) * LDEC;

    launch_gemm<64, 64, 128, 0, 1, 0, 1, 0>(stream, dcur_bf, base,
                                            dec_qkv1_b + (size_t)i * 3 * DM, qkv_bf,
                                            M, 3 * DM, DM, DM, DM, 3 * DM,
                                            nullptr, nullptr, VT, 2 * DM);
    flash_attn<1><<<dim3(LL / 64, BB * NH), 256, 0, stream>>>(
        qkv_bf, 3 * DM, qkv_bf + DM, 3 * DM, VT, ab_bf);
    launch_gemm<64, 32, 128, 0, 0, 0, 0, 0>(stream, ab_bf, base + 3 * DD,
                                            dec_o1_b + (size_t)i * DM, tmp,
                                            M, DM, DM, DM, DM, DM, dcur);
    add_ln1<<<M, 256, 0, stream>>>(tmp, dec_ln_w + (size_t)i * DM, dec_ln_b + (size_t)i * DM, d1b, d1b_bf);

    launch_gemm<64, 32, 128, 0, 1, 0, 0, 0>(stream, d1b_bf, WTq + (size_t)i * DD,
                                            dec_qkv2_b + (size_t)i * 3 * DM, q_bf,
                                            M, DM, DM, DM, DM, DM);
    flash_attn<1><<<dim3(LL / 64, BB * NH), 256, 0, stream>>>(
        q_bf, DM, kvall + (size_t)2048 * i, 8192, VT4 + (size_t)i * VT4S, ab_bf);
    launch_gemm<64, 32, 128, 0, 0, 0, 0, 0>(stream, ab_bf, base + 4 * DD,
                                            dec_o2_b + (size_t)i * DM, tmp,
                                            M, DM, DM, DM, DM, DM, d1b);
    add_ln1<<<M, 256, 0, stream>>>(tmp, dec_ln_w + (size_t)i * DM, dec_ln_b + (size_t)i * DM, d2b, d2b_bf);

    launch_gemm<128, 64, 64, 1, 1, 0, 0, 0>(stream, d2b_bf, base + 5 * DD,
                                            dec_b1 + (size_t)i * DFF, hid_bf,
                                            M, DFF, DM, DM, DM, DFF);
    launch_gemm<64, 32, 128, 0, 0, 0, 0, 0>(stream, hid_bf, base + 5 * DD + DF,
                                            dec_b2 + (size_t)i * DM, dcur,
                                            M, DM, DFF, DFF, DFF, DM, d2b, dcur_bf);
  }

  // ---- output projection (BN=128/BK=64, NTC coalesced NT stores) ----
  {
    TJobs J{}; int tot = 0;
    add_tjob(J, tot, out_w, WT, DM, VTOK, 1);
    transpose_multi<<<tot, 256, 0, stream>>>(J);
  }
  launch_gemm<128, 128, 64, 0, 0, 1, 0, 0, 1>(stream, dcur_bf, WT, out_b, out,
                                              M, VTOK, DM, DM, DM, VTOK);
}